// Round 11
// baseline (6772.408 us; speedup 1.0000x reference)
//
#include <hip/hip_runtime.h>

#define B_    1024
#define H_    2112
#define FH    8448   // 4*H
#define IN_   99
#define TENC  50
#define SEQ   25
#define K0    2240   // 128 (padded IN) + 2112
#define K1    4224   // 2112 + 2112
#define LDX0  2240
#define LDX1  4224

typedef __bf16 bf16;
typedef __bf16 bf16x8 __attribute__((ext_vector_type(8)));
typedef __bf16 bf16x4 __attribute__((ext_vector_type(4)));
typedef float  f32x4  __attribute__((ext_vector_type(4)));

__device__ __forceinline__ void gload_lds16(const void* g, void* l) {
  __builtin_amdgcn_global_load_lds(
      (const __attribute__((address_space(1))) void*)g,
      (__attribute__((address_space(3))) void*)l, 16, 0, 0);
}

__device__ __forceinline__ float sigf(float x) { return 1.f / (1.f + __expf(-x)); }
__device__ __forceinline__ float tanhfast(float x) { return 1.f - 2.f / (__expf(2.f * x) + 1.f); }

// ---------------------------------------------------------------------------
// Fused gates-GEMM + LSTM cell — K-duty-split wave pairs on the r8 skeleton.
// Block 128(M) x 128 gate-cols (4 sec x 32 h); grid 528 = 8 mb x 66 hb,
// hc-chunked XCD map (r4-proven).  4 waves = (wm 0/1) x (ks 0/1).
// Wave (wm,ks): FULL 64x128-gate wave-tile (acc[4][8]), K-tiles of parity ks
// only -> ds_read per wave-MFMA drops 0.5KB -> 0.375KB (the r4==r8 common
// bound).  All 256 threads co-stage every K32 tile; stage-ahead static double
// buffer + plain __syncthreads (r8-proven).  Epilogue: 2-round LDS partial
// reduce (ks=1 -> ks=0), then fused cell by ks=0 waves.  LDS 32KB.
// ---------------------------------------------------------------------------
__global__ __launch_bounds__(256, 2)
void lstm_gemm_cell(const bf16* __restrict__ X, int lda, int K,
                    const bf16* __restrict__ W,
                    const float* __restrict__ bsum,   // 4H combined bias
                    float* __restrict__ Cst,          // B x H fp32, in-place
                    bf16* __restrict__ d1, int ld1,   // h_new dest 1
                    bf16* __restrict__ d2, int ld2)   // h_new dest 2 (optional)
{
  __shared__ __align__(16) bf16 S[4 * 4096];   // 32 KB: As0|As1|Bs0|Bs1
  bf16* const As0 = S;
  bf16* const As1 = S + 4096;
  bf16* const Bs0 = S + 8192;
  bf16* const Bs1 = S + 12288;

  const int vid = (blockIdx.x & 7) * 66 + (blockIdx.x >> 3);
  const int hb  = vid >> 3;                             // 0..65
  const int hc0 = hb * 32;
  const int m0  = (vid & 7) * 128;

  const int tid  = threadIdx.x;                         // 0..255
  const int srow = tid >> 2;                            // 0..63
  const int scol = (tid & 3) * 8;                       // bf16 elems (linear)

  const bf16* Ab = X + (size_t)(m0 + srow) * lda + scol;
  // B LDS row n = it*64 + srow; n = sec*32 + hl (sec = nf>>1? no: sec = n>>5)
  //   -> W row = (it*2 + (srow>>5))*H + hc0 + (srow&31)
  const bf16* Bb = W + ((size_t)(srow >> 5) * H_ + hc0 + (srow & 31)) * K + scol;
  const size_t HK2 = (size_t)2 * H_ * K;

  const int lane = tid & 63;
  const int wv = tid >> 6;
  const int wm = wv >> 1, ks = wv & 1;
  const int lr = lane & 15, lq = lane >> 4;

  f32x4 acc[4][8];
#pragma unroll
  for (int a = 0; a < 4; ++a)
#pragma unroll
    for (int b = 0; b < 8; ++b) acc[a][b] = (f32x4){0.f, 0.f, 0.f, 0.f};

#define STAGE(kt, AD, BD) do {                                               \
    const int ko_ = (kt) * 32;                                               \
    gload_lds16(Ab + ko_,                    &AD[tid * 8]);                  \
    gload_lds16(Ab + (size_t)64 * lda + ko_, &AD[2048 + tid * 8]);           \
    gload_lds16(Bb + ko_,                    &BD[tid * 8]);                  \
    gload_lds16(Bb + HK2 + ko_,              &BD[2048 + tid * 8]);           \
  } while (0)

#define COMPUTE(AS, BS) do {                                                 \
    bf16x8 af_[4], bf_[8];                                                   \
    _Pragma("unroll")                                                        \
    for (int mi = 0; mi < 4; ++mi)                                           \
      af_[mi] = *(const bf16x8*)&AS[(wm * 64 + mi * 16 + lr) * 32 + lq * 8]; \
    _Pragma("unroll")                                                        \
    for (int nf = 0; nf < 8; ++nf)                                           \
      bf_[nf] = *(const bf16x8*)&BS[(nf * 16 + lr) * 32 + lq * 8];           \
    _Pragma("unroll")                                                        \
    for (int mi = 0; mi < 4; ++mi)                                           \
      _Pragma("unroll")                                                      \
      for (int nf = 0; nf < 8; ++nf)                                         \
        acc[mi][nf] = __builtin_amdgcn_mfma_f32_16x16x32_bf16(               \
            af_[mi], bf_[nf], acc[mi][nf], 0, 0, 0);                         \
  } while (0)

  const int KT = K >> 5;        // 70 (L0) or 132 (L1) — always even
  STAGE(0, As0, Bs0);
  __syncthreads();
  for (int kt = 0; kt < KT; kt += 2) {
    STAGE(kt + 1, As1, Bs1);            // flies under compute of tile kt
    if (ks == 0) COMPUTE(As0, Bs0);     // even-parity duty
    __syncthreads();
    if (kt + 2 < KT) STAGE(kt + 2, As0, Bs0);
    if (ks == 1) COMPUTE(As1, Bs1);     // odd-parity duty
    __syncthreads();
  }
#undef COMPUTE
#undef STAGE

  // cross-parity partial reduce: ks=1 -> ks=0, one wm per round (32KB scratch)
  f32x4* red = (f32x4*)S;               // 2048 f32x4
#pragma unroll
  for (int round = 0; round < 2; ++round) {
    if (wm == round && ks == 1) {
#pragma unroll
      for (int mi = 0; mi < 4; ++mi)
#pragma unroll
        for (int nf = 0; nf < 8; ++nf)
          red[(mi * 8 + nf) * 64 + lane] = acc[mi][nf];
    }
    __syncthreads();
    if (wm == round && ks == 0) {
#pragma unroll
      for (int mi = 0; mi < 4; ++mi)
#pragma unroll
        for (int nf = 0; nf < 8; ++nf)
          acc[mi][nf] += red[(mi * 8 + nf) * 64 + lane];
    }
    __syncthreads();
  }

  if (ks != 0) return;

  // epilogue: LSTM cell.  nf = sec*2 + hh;  lane owns h-cols hc0+hh*16+lr.
#pragma unroll
  for (int hh = 0; hh < 2; ++hh) {
    const int hc = hc0 + hh * 16 + lr;
    const float bi  = bsum[hc];
    const float bff = bsum[H_ + hc];
    const float bg  = bsum[2 * H_ + hc];
    const float bo  = bsum[3 * H_ + hc];
#pragma unroll
    for (int mi = 0; mi < 4; ++mi) {
#pragma unroll
      for (int r = 0; r < 4; ++r) {
        const int m = m0 + wm * 64 + mi * 16 + lq * 4 + r;
        const float gi = acc[mi][0 + hh][r] + bi;
        const float gf = acc[mi][2 + hh][r] + bff;
        const float gg = acc[mi][4 + hh][r] + bg;
        const float go = acc[mi][6 + hh][r] + bo;
        const size_t ci = (size_t)m * H_ + hc;
        const float c_old = Cst[ci];
        const float cn = sigf(gf) * c_old + sigf(gi) * tanhfast(gg);
        const float hn = sigf(go) * tanhfast(cn);
        Cst[ci] = cn;
        const bf16 hb2 = (bf16)hn;
        d1[(size_t)m * ld1 + hc] = hb2;
        if (d2) d2[(size_t)m * ld2 + hc] = hb2;
      }
    }
  }
}

// ---------------------------------------------------------------------------
// out-GEMM (r4-exact): pre = h1n @ W_out + b_out + prev.
// 256 blocks of 4 rows; K=2112 as 33 tiles of 64 split {9,8,8,8}; LDS reduce.
// ---------------------------------------------------------------------------
__global__ __launch_bounds__(256, 1)
void out_gemm(const bf16* __restrict__ Hin,   // X1next + 2112, row stride 4224
              const bf16* __restrict__ Wo,    // 112 x 2112 (transposed, padded)
              const float* __restrict__ b_out,
              float* __restrict__ prev,       // B x 112 fp32
              bf16* __restrict__ X0n,         // write bf16 pre at cols 0..99
              float* __restrict__ out, int t)
{
  __shared__ float red[4][4][112];
  const int tid = threadIdx.x;
  const int m0 = blockIdx.x * 4;
  const int lane = tid & 63, wv = tid >> 6;
  const int lr = lane & 15, lq = lane >> 4, lk = lq * 8;

  f32x4 acc[7];
#pragma unroll
  for (int b = 0; b < 7; ++b) acc[b] = (f32x4){0.f, 0.f, 0.f, 0.f};

  const int start = (wv == 0) ? 0 : (1 + wv * 8);   // {0,9,17,25}
  const int cnt = (wv == 0) ? 9 : 8;                // 33 K-tiles of 64 total

  for (int kt = start; kt < start + cnt; ++kt) {
    const int ko = kt * 64;
    bf16x8 av[2], bv[7][2];
#pragma unroll
    for (int kc = 0; kc < 2; ++kc)
      av[kc] = *(const bf16x8*)&Hin[(size_t)(m0 + (lr & 3)) * LDX1 + ko + kc * 32 + lk];
#pragma unroll
    for (int nf = 0; nf < 7; ++nf)
#pragma unroll
      for (int kc = 0; kc < 2; ++kc)
        bv[nf][kc] = *(const bf16x8*)&Wo[(size_t)(nf * 16 + lr) * H_ + ko + kc * 32 + lk];
#pragma unroll
    for (int nf = 0; nf < 7; ++nf)
#pragma unroll
      for (int kc = 0; kc < 2; ++kc)
        acc[nf] = __builtin_amdgcn_mfma_f32_16x16x32_bf16(av[kc], bv[nf][kc], acc[nf], 0, 0, 0);
  }

  if (lq == 0) {
#pragma unroll
    for (int nf = 0; nf < 7; ++nf)
#pragma unroll
      for (int r = 0; r < 4; ++r)
        red[wv][r][nf * 16 + lr] = acc[nf][r];
  }
  __syncthreads();

  for (int idx = tid; idx < 4 * 112; idx += 256) {
    const int ml = idx / 112, n = idx - ml * 112;
    if (n < IN_) {
      const int m = m0 + ml;
      float s = red[0][ml][n] + red[1][ml][n] + red[2][ml][n] + red[3][ml][n] + b_out[n];
      const float pre = s + prev[m * 112 + n];
      prev[m * 112 + n] = pre;
      out[((size_t)m * SEQ + t) * IN_ + n] = pre;
      X0n[(size_t)m * LDX0 + n] = (bf16)pre;
    }
  }
}

// ---------------------------------------------------------------------------
// init: h0 = mean(hidden), h1 = (global_t + sum hidden)/51, c0 = c1 = mean(cell)
// ---------------------------------------------------------------------------
__global__ void init_state(const float* __restrict__ hs, const float* __restrict__ cs,
                           const float* __restrict__ gts,
                           bf16* __restrict__ X0a, bf16* __restrict__ X1a,
                           float* __restrict__ c0, float* __restrict__ c1)
{
  const int h4 = blockIdx.x * 256 + threadIdx.x;
  if (h4 >= 528) return;
  const int b = blockIdx.y;
  const float4* hp = (const float4*)(hs + (size_t)b * TENC * H_) + h4;
  const float4* cp = (const float4*)(cs + (size_t)b * TENC * H_) + h4;
  float4 sh = {0.f, 0.f, 0.f, 0.f}, sc = {0.f, 0.f, 0.f, 0.f};
  for (int tt = 0; tt < TENC; ++tt) {
    float4 a = hp[tt * 528];
    sh.x += a.x; sh.y += a.y; sh.z += a.z; sh.w += a.w;
    float4 c = cp[tt * 528];
    sc.x += c.x; sc.y += c.y; sc.z += c.z; sc.w += c.w;
  }
  const float4 g = ((const float4*)(gts + (size_t)b * H_))[h4];
  const float4 c0v = {sc.x / 50.f, sc.y / 50.f, sc.z / 50.f, sc.w / 50.f};
  ((float4*)(c0 + (size_t)b * H_))[h4] = c0v;
  ((float4*)(c1 + (size_t)b * H_))[h4] = c0v;
  bf16x4 h0b = {(bf16)(sh.x / 50.f), (bf16)(sh.y / 50.f), (bf16)(sh.z / 50.f), (bf16)(sh.w / 50.f)};
  *(bf16x4*)&X0a[(size_t)b * LDX0 + 128 + h4 * 4] = h0b;
  bf16x4 h1b = {(bf16)((sh.x + g.x) / 51.f), (bf16)((sh.y + g.y) / 51.f),
                (bf16)((sh.z + g.z) / 51.f), (bf16)((sh.w + g.w) / 51.f)};
  *(bf16x4*)&X1a[(size_t)b * LDX1 + 2112 + h4 * 4] = h1b;
}

__global__ void init_prev(const float* __restrict__ p, float* __restrict__ prev,
                          bf16* __restrict__ X0a, bf16* __restrict__ X0b)
{
  const int idx = blockIdx.x * 256 + threadIdx.x;   // B*128
  const int b = idx >> 7, n = idx & 127;
  const float v = (n < IN_) ? p[(size_t)b * IN_ + n] : 0.f;
  if (n < 112) prev[b * 112 + n] = v;
  X0a[(size_t)b * LDX0 + n] = (bf16)v;
  X0b[(size_t)b * LDX0 + n] = (bf16)0.f;   // pads stay zero; 0..99 overwritten step 0
}

// ---------------------------------------------------------------------------
// weight packing (fp32 -> bf16, concatenated / transposed)
// ---------------------------------------------------------------------------
__global__ void pack_w0(const float* __restrict__ Wih, const float* __restrict__ Whh,
                        bf16* __restrict__ Wc)
{
  const int n = blockIdx.x;
  const float* a = Wih + (size_t)n * IN_;
  const float* b = Whh + (size_t)n * H_;
  bf16* d = Wc + (size_t)n * K0;
  for (int k = threadIdx.x; k < K0; k += 256) {
    float v = (k < IN_) ? a[k] : ((k >= 128) ? b[k - 128] : 0.f);
    d[k] = (bf16)v;
  }
}

__global__ void pack_w1(const float* __restrict__ Wih, const float* __restrict__ Whh,
                        bf16* __restrict__ Wc)
{
  const int n = blockIdx.x;
  bf16* d = Wc + (size_t)n * K1;
  for (int k = threadIdx.x; k < K1; k += 256)
    d[k] = (bf16)((k < H_) ? Wih[(size_t)n * H_ + k] : Whh[(size_t)n * H_ + k - H_]);
}

__global__ void pack_wo(const float* __restrict__ W, bf16* __restrict__ Wo)
{
  const int n = blockIdx.x;   // 0..111
  for (int k = threadIdx.x; k < H_; k += 256)
    Wo[(size_t)n * H_ + k] = (n < IN_) ? (bf16)W[(size_t)k * IN_ + n] : (bf16)0.f;
}

__global__ void pack_bias(const float* __restrict__ bi0, const float* __restrict__ bh0,
                          const float* __restrict__ bi1, const float* __restrict__ bh1,
                          float* __restrict__ bs0, float* __restrict__ bs1)
{
  const int i = blockIdx.x * 256 + threadIdx.x;
  if (i < FH) { bs0[i] = bi0[i] + bh0[i]; bs1[i] = bi1[i] + bh1[i]; }
}

// ---------------------------------------------------------------------------
extern "C" void kernel_launch(void* const* d_in, const int* in_sizes, int n_in,
                              void* d_out, int out_size, void* d_ws, size_t ws_size,
                              hipStream_t stream)
{
  (void)in_sizes; (void)n_in; (void)out_size; (void)ws_size;
  const float* hs   = (const float*)d_in[0];
  const float* cs   = (const float*)d_in[1];
  const float* gts  = (const float*)d_in[2];
  const float* p    = (const float*)d_in[3];
  const float* Wih0 = (const float*)d_in[4];
  const float* bih0 = (const float*)d_in[5];
  const float* Whh0 = (const float*)d_in[6];
  const float* bhh0 = (const float*)d_in[7];
  const float* Wih1 = (const float*)d_in[8];
  const float* bih1 = (const float*)d_in[9];
  const float* Whh1 = (const float*)d_in[10];
  const float* bhh1 = (const float*)d_in[11];
  const float* Wout = (const float*)d_in[12];
  const float* bout = (const float*)d_in[13];
  float* out = (float*)d_out;

  char* ws = (char*)d_ws;
  size_t off = 0;
  auto alloc = [&](size_t bytes) -> void* {
    void* q = ws + off; off += (bytes + 255) & ~(size_t)255; return q;
  };
  bf16* Wc0 = (bf16*)alloc((size_t)FH * K0 * 2);
  bf16* Wc1 = (bf16*)alloc((size_t)FH * K1 * 2);
  bf16* Wo  = (bf16*)alloc((size_t)112 * H_ * 2);
  float* bs0 = (float*)alloc((size_t)FH * 4);
  float* bs1 = (float*)alloc((size_t)FH * 4);
  bf16* X0[2] = {(bf16*)alloc((size_t)B_ * LDX0 * 2), (bf16*)alloc((size_t)B_ * LDX0 * 2)};
  bf16* X1[2] = {(bf16*)alloc((size_t)B_ * LDX1 * 2), (bf16*)alloc((size_t)B_ * LDX1 * 2)};
  float* c0  = (float*)alloc((size_t)B_ * H_ * 4);
  float* c1  = (float*)alloc((size_t)B_ * H_ * 4);
  float* prev = (float*)alloc((size_t)B_ * 112 * 4);

  pack_w0<<<FH, 256, 0, stream>>>(Wih0, Whh0, Wc0);
  pack_w1<<<FH, 256, 0, stream>>>(Wih1, Whh1, Wc1);
  pack_wo<<<112, 256, 0, stream>>>(Wout, Wo);
  pack_bias<<<(FH + 255) / 256, 256, 0, stream>>>(bih0, bhh0, bih1, bhh1, bs0, bs1);
  init_prev<<<(B_ * 128) / 256, 256, 0, stream>>>(p, prev, X0[0], X0[1]);
  init_state<<<dim3(3, B_), 256, 0, stream>>>(hs, cs, gts, X0[0], X1[0], c0, c1);

  for (int t = 0; t < SEQ; ++t) {
    const int cur = t & 1, nxt = cur ^ 1;
    // layer 0: reads X0[cur] = [prev_bf | h0]; writes c0, h0n -> X1[cur] and X0[nxt]+128
    lstm_gemm_cell<<<528, 256, 0, stream>>>(
        X0[cur], LDX0, K0, Wc0, bs0, c0, X1[cur], LDX1, X0[nxt] + 128, LDX0);
    // layer 1: reads X1[cur] = [h0n | h1]; writes c1, h1n -> X1[nxt]+2112
    lstm_gemm_cell<<<528, 256, 0, stream>>>(
        X1[cur], LDX1, K1, Wc1, bs1, c1, X1[nxt] + 2112, LDX1, (bf16*)nullptr, 0);
    // out: pre = h1n @ W_out + b_out + prev; writes out[:,t,:], prev, X0[nxt] cols 0..99
    out_gemm<<<256, 256, 0, stream>>>(X1[nxt] + 2112, Wo, bout, prev, X0[nxt], out, t);
  }
}

// Round 12
// 4524.684 us; speedup vs baseline: 1.4968x; 1.4968x over previous
//
#include <hip/hip_runtime.h>

#define B_    1024
#define H_    2112
#define FH    8448   // 4*H
#define IN_   99
#define TENC  50
#define SEQ   25
#define K0    2240   // 128 (padded IN) + 2112
#define K1    4224   // 2112 + 2112
#define LDP   128    // pre-buffer row stride (bf16)
#define LDX1  4224

typedef __bf16 bf16;
typedef __bf16 bf16x8 __attribute__((ext_vector_type(8)));
typedef __bf16 bf16x4 __attribute__((ext_vector_type(4)));
typedef float  f32x4  __attribute__((ext_vector_type(4)));

__device__ __forceinline__ void gload_lds16(const void* g, void* l) {
  __builtin_amdgcn_global_load_lds(
      (const __attribute__((address_space(1))) void*)g,
      (__attribute__((address_space(3))) void*)l, 16, 0, 0);
}

__device__ __forceinline__ float sigf(float x) { return 1.f / (1.f + __expf(-x)); }
__device__ __forceinline__ float tanhfast(float x) { return 1.f - 2.f / (__expf(2.f * x) + 1.f); }

// ---------------------------------------------------------------------------
// Fused gates-GEMM + LSTM cell — r8 champion structure (4666us), exact sync
// discipline: tile 128(M) x 32(h) => 128 gate-cols; 4 waves (wm,wn)=2x2;
// BK=32 (64B LDS rows -> conflict-free b128 reads by construction);
// stage-ahead static double buffers + ONE __syncthreads per K-tile.
// CHANGE vs r8: A comes from TWO segments — pre-buffer (kt<KB, ld 128) and
// X1 h-segment (kt>=KB, ld 4224) — removing L0's duplicate h0n write.
// Grid 528 = 8 mb x 66 hb, hc-chunked XCD mapping (r4-proven).
// ---------------------------------------------------------------------------
__global__ __launch_bounds__(256, 2)
void lstm_gemm_cell(const bf16* __restrict__ Xpre,  // pre segment (may be unused)
                    const bf16* __restrict__ Xh,    // h segment base
                    int KB,                          // # of 32-K tiles in pre (4 or 0)
                    int K,
                    const bf16* __restrict__ W,
                    const float* __restrict__ bsum,  // 4H combined bias
                    float* __restrict__ Cst,         // B x H fp32, in-place
                    bf16* __restrict__ d1)           // h_new dest (ld 4224)
{
  __shared__ __align__(16) bf16 As0[128 * 32];   // 8 KB each
  __shared__ __align__(16) bf16 As1[128 * 32];
  __shared__ __align__(16) bf16 Bs0[128 * 32];
  __shared__ __align__(16) bf16 Bs1[128 * 32];

  // XCD-chunked: 528 blocks, 66 consecutive vids per XCD; vid walks mb fast,
  // hb slow -> same-XCD co-resident blocks share the same weight panel.
  const int vid = (blockIdx.x & 7) * 66 + (blockIdx.x >> 3);
  const int hb  = vid >> 3;                             // 0..65
  const int hc0 = hb * 32;
  const int m0  = (vid & 7) * 128;

  const int tid  = threadIdx.x;                         // 0..255
  const int srow = tid >> 2;                            // 0..63
  const int scol = (tid & 3) * 8;                       // bf16 elems (linear)

  // A sources: pre tiles kt<KB at ld 128; h tiles at ld 4224, col -KB*32.
  const bf16* ApreT = Xpre + (size_t)(m0 + srow) * LDP + scol;
  const bf16* AhT   = Xh + (size_t)(m0 + srow) * LDX1 + scol - KB * 32;
  // B rows n = it*64 + srow, n = sec*32 + h_local:
  //   W row = (it*2 + (srow>>5))*H + hc0 + (srow&31)
  const bf16* Bb = W + ((size_t)(srow >> 5) * H_ + hc0 + (srow & 31)) * K + scol;
  const size_t HK2 = (size_t)2 * H_ * K;

  const int lane = tid & 63;
  const int wv = tid >> 6;
  const int wm = wv >> 1, wn = wv & 1;
  const int lr = lane & 15, lq = lane >> 4;

  f32x4 acc[4][4];
#pragma unroll
  for (int a = 0; a < 4; ++a)
#pragma unroll
    for (int b = 0; b < 4; ++b) acc[a][b] = (f32x4){0.f, 0.f, 0.f, 0.f};

#define STAGE(kt, AD, BD) do {                                              \
    const int ko_ = (kt) * 32;                                              \
    const bf16* a_ = ((kt) < KB) ? (ApreT + ko_) : (AhT + ko_);             \
    const size_t alda_ = ((kt) < KB) ? (size_t)LDP : (size_t)LDX1;          \
    gload_lds16(a_,                    &AD[0 * 2048 + tid * 8]);            \
    gload_lds16(a_ + 64 * alda_,       &AD[1 * 2048 + tid * 8]);            \
    gload_lds16(Bb + ko_,              &BD[0 * 2048 + tid * 8]);            \
    gload_lds16(Bb + HK2 + ko_,        &BD[1 * 2048 + tid * 8]);            \
  } while (0)

#define COMPUTE(AS, BS) do {                                                \
    bf16x8 af_[4], bf_[4];                                                  \
    _Pragma("unroll")                                                       \
    for (int mi = 0; mi < 4; ++mi)                                          \
      af_[mi] = *(const bf16x8*)&AS[(wm * 64 + mi * 16 + lr) * 32 + lq * 8];\
    _Pragma("unroll")                                                       \
    for (int nf = 0; nf < 4; ++nf)                                          \
      bf_[nf] = *(const bf16x8*)&BS[(nf * 32 + wn * 16 + lr) * 32 + lq * 8];\
    _Pragma("unroll")                                                       \
    for (int mi = 0; mi < 4; ++mi)                                          \
      _Pragma("unroll")                                                     \
      for (int nf = 0; nf < 4; ++nf)                                        \
        acc[mi][nf] = __builtin_amdgcn_mfma_f32_16x16x32_bf16(              \
            af_[mi], bf_[nf], acc[mi][nf], 0, 0, 0);                        \
  } while (0)

  const int KT = K >> 5;        // 70 (L0) or 132 (L1), always even
  STAGE(0, As0, Bs0);
  __syncthreads();
  for (int kt = 0; kt < KT; kt += 2) {
    STAGE(kt + 1, As1, Bs1);            // fly under compute of tile kt
    COMPUTE(As0, Bs0);
    __syncthreads();                    // drains stage(kt+1), publishes As1/Bs1
    if (kt + 2 < KT) STAGE(kt + 2, As0, Bs0);
    COMPUTE(As1, Bs1);
    __syncthreads();
  }
#undef STAGE
#undef COMPUTE

  // epilogue: LSTM cell (lane owns h-col hc for 16 m-rows)
  const int hc = hc0 + wn * 16 + lr;
  const float bi  = bsum[hc];
  const float bff = bsum[H_ + hc];
  const float bg  = bsum[2 * H_ + hc];
  const float bo  = bsum[3 * H_ + hc];

#pragma unroll
  for (int mi = 0; mi < 4; ++mi) {
#pragma unroll
    for (int r = 0; r < 4; ++r) {
      const int m = m0 + wm * 64 + mi * 16 + lq * 4 + r;
      const float gi = acc[mi][0][r] + bi;
      const float gf = acc[mi][1][r] + bff;
      const float gg = acc[mi][2][r] + bg;
      const float go = acc[mi][3][r] + bo;
      const size_t ci = (size_t)m * H_ + hc;
      const float c_old = Cst[ci];
      const float cn = sigf(gf) * c_old + sigf(gi) * tanhfast(gg);
      const float hn = sigf(go) * tanhfast(cn);
      Cst[ci] = cn;
      d1[(size_t)m * LDX1 + hc] = (bf16)hn;
    }
  }
}

// ---------------------------------------------------------------------------
// out-GEMM (champion-exact): pre = h1n @ W_out + b_out + prev.
// 256 blocks of 4 rows; K=2112 as 33 tiles of 64 split {9,8,8,8}; LDS reduce.
// ---------------------------------------------------------------------------
__global__ __launch_bounds__(256, 1)
void out_gemm(const bf16* __restrict__ Hin,   // X1next + 2112, row stride 4224
              const bf16* __restrict__ Wo,    // 112 x 2112 (transposed, padded)
              const float* __restrict__ b_out,
              float* __restrict__ prev,       // B x 112 fp32
              bf16* __restrict__ X0n,         // write bf16 pre at cols 0..99 (ld 128)
              float* __restrict__ out, int t)
{
  __shared__ float red[4][4][112];
  const int tid = threadIdx.x;
  const int m0 = blockIdx.x * 4;
  const int lane = tid & 63, wv = tid >> 6;
  const int lr = lane & 15, lq = lane >> 4, lk = lq * 8;

  f32x4 acc[7];
#pragma unroll
  for (int b = 0; b < 7; ++b) acc[b] = (f32x4){0.f, 0.f, 0.f, 0.f};

  const int start = (wv == 0) ? 0 : (1 + wv * 8);   // {0,9,17,25}
  const int cnt = (wv == 0) ? 9 : 8;                // 33 K-tiles of 64 total

  for (int kt = start; kt < start + cnt; ++kt) {
    const int ko = kt * 64;
    bf16x8 av[2], bv[7][2];
#pragma unroll
    for (int kc = 0; kc < 2; ++kc)
      av[kc] = *(const bf16x8*)&Hin[(size_t)(m0 + (lr & 3)) * LDX1 + ko + kc * 32 + lk];
#pragma unroll
    for (int nf = 0; nf < 7; ++nf)
#pragma unroll
      for (int kc = 0; kc < 2; ++kc)
        bv[nf][kc] = *(const bf16x8*)&Wo[(size_t)(nf * 16 + lr) * H_ + ko + kc * 32 + lk];
#pragma unroll
    for (int nf = 0; nf < 7; ++nf)
#pragma unroll
      for (int kc = 0; kc < 2; ++kc)
        acc[nf] = __builtin_amdgcn_mfma_f32_16x16x32_bf16(av[kc], bv[nf][kc], acc[nf], 0, 0, 0);
  }

  if (lq == 0) {
#pragma unroll
    for (int nf = 0; nf < 7; ++nf)
#pragma unroll
      for (int r = 0; r < 4; ++r)
        red[wv][r][nf * 16 + lr] = acc[nf][r];
  }
  __syncthreads();

  for (int idx = tid; idx < 4 * 112; idx += 256) {
    const int ml = idx / 112, n = idx - ml * 112;
    if (n < IN_) {
      const int m = m0 + ml;
      float s = red[0][ml][n] + red[1][ml][n] + red[2][ml][n] + red[3][ml][n] + b_out[n];
      const float pre = s + prev[m * 112 + n];
      prev[m * 112 + n] = pre;
      out[((size_t)m * SEQ + t) * IN_ + n] = pre;
      X0n[(size_t)m * LDP + n] = (bf16)pre;
    }
  }
}

// ---------------------------------------------------------------------------
// init: h0 -> X1[1] cols 0.., h1 -> X1[0] cols 2112.., c0 = c1 = mean(cell)
// ---------------------------------------------------------------------------
__global__ void init_state(const float* __restrict__ hs, const float* __restrict__ cs,
                           const float* __restrict__ gts,
                           bf16* __restrict__ X1_1, bf16* __restrict__ X1_0,
                           float* __restrict__ c0, float* __restrict__ c1)
{
  const int h4 = blockIdx.x * 256 + threadIdx.x;
  if (h4 >= 528) return;
  const int b = blockIdx.y;
  const float4* hp = (const float4*)(hs + (size_t)b * TENC * H_) + h4;
  const float4* cp = (const float4*)(cs + (size_t)b * TENC * H_) + h4;
  float4 sh = {0.f, 0.f, 0.f, 0.f}, sc = {0.f, 0.f, 0.f, 0.f};
  for (int tt = 0; tt < TENC; ++tt) {
    float4 a = hp[tt * 528];
    sh.x += a.x; sh.y += a.y; sh.z += a.z; sh.w += a.w;
    float4 c = cp[tt * 528];
    sc.x += c.x; sc.y += c.y; sc.z += c.z; sc.w += c.w;
  }
  const float4 g = ((const float4*)(gts + (size_t)b * H_))[h4];
  const float4 c0v = {sc.x / 50.f, sc.y / 50.f, sc.z / 50.f, sc.w / 50.f};
  ((float4*)(c0 + (size_t)b * H_))[h4] = c0v;
  ((float4*)(c1 + (size_t)b * H_))[h4] = c0v;
  bf16x4 h0b = {(bf16)(sh.x / 50.f), (bf16)(sh.y / 50.f), (bf16)(sh.z / 50.f), (bf16)(sh.w / 50.f)};
  *(bf16x4*)&X1_1[(size_t)b * LDX1 + h4 * 4] = h0b;
  bf16x4 h1b = {(bf16)((sh.x + g.x) / 51.f), (bf16)((sh.y + g.y) / 51.f),
                (bf16)((sh.z + g.z) / 51.f), (bf16)((sh.w + g.w) / 51.f)};
  *(bf16x4*)&X1_0[(size_t)b * LDX1 + 2112 + h4 * 4] = h1b;
}

__global__ void init_prev(const float* __restrict__ p, float* __restrict__ prev,
                          bf16* __restrict__ P0a, bf16* __restrict__ P0b)
{
  const int idx = blockIdx.x * 256 + threadIdx.x;   // B*128
  const int b = idx >> 7, n = idx & 127;
  const float v = (n < IN_) ? p[(size_t)b * IN_ + n] : 0.f;
  if (n < 112) prev[b * 112 + n] = v;
  P0a[(size_t)b * LDP + n] = (bf16)v;
  P0b[(size_t)b * LDP + n] = (bf16)0.f;   // pads stay zero; cols 0..99 overwritten by out(0)
}

// ---------------------------------------------------------------------------
// weight packing (fp32 -> bf16, concatenated / transposed)
// ---------------------------------------------------------------------------
__global__ void pack_w0(const float* __restrict__ Wih, const float* __restrict__ Whh,
                        bf16* __restrict__ Wc)
{
  const int n = blockIdx.x;
  const float* a = Wih + (size_t)n * IN_;
  const float* b = Whh + (size_t)n * H_;
  bf16* d = Wc + (size_t)n * K0;
  for (int k = threadIdx.x; k < K0; k += 256) {
    float v = (k < IN_) ? a[k] : ((k >= 128) ? b[k - 128] : 0.f);
    d[k] = (bf16)v;
  }
}

__global__ void pack_w1(const float* __restrict__ Wih, const float* __restrict__ Whh,
                        bf16* __restrict__ Wc)
{
  const int n = blockIdx.x;
  bf16* d = Wc + (size_t)n * K1;
  for (int k = threadIdx.x; k < K1; k += 256)
    d[k] = (bf16)((k < H_) ? Wih[(size_t)n * H_ + k] : Whh[(size_t)n * H_ + k - H_]);
}

__global__ void pack_wo(const float* __restrict__ W, bf16* __restrict__ Wo)
{
  const int n = blockIdx.x;   // 0..111
  for (int k = threadIdx.x; k < H_; k += 256)
    Wo[(size_t)n * H_ + k] = (n < IN_) ? (bf16)W[(size_t)k * IN_ + n] : (bf16)0.f;
}

__global__ void pack_bias(const float* __restrict__ bi0, const float* __restrict__ bh0,
                          const float* __restrict__ bi1, const float* __restrict__ bh1,
                          float* __restrict__ bs0, float* __restrict__ bs1)
{
  const int i = blockIdx.x * 256 + threadIdx.x;
  if (i < FH) { bs0[i] = bi0[i] + bh0[i]; bs1[i] = bi1[i] + bh1[i]; }
}

// ---------------------------------------------------------------------------
extern "C" void kernel_launch(void* const* d_in, const int* in_sizes, int n_in,
                              void* d_out, int out_size, void* d_ws, size_t ws_size,
                              hipStream_t stream)
{
  (void)in_sizes; (void)n_in; (void)out_size; (void)ws_size;
  const float* hs   = (const float*)d_in[0];
  const float* cs   = (const float*)d_in[1];
  const float* gts  = (const float*)d_in[2];
  const float* p    = (const float*)d_in[3];
  const float* Wih0 = (const float*)d_in[4];
  const float* bih0 = (const float*)d_in[5];
  const float* Whh0 = (const float*)d_in[6];
  const float* bhh0 = (const float*)d_in[7];
  const float* Wih1 = (const float*)d_in[8];
  const float* bih1 = (const float*)d_in[9];
  const float* Whh1 = (const float*)d_in[10];
  const float* bhh1 = (const float*)d_in[11];
  const float* Wout = (const float*)d_in[12];
  const float* bout = (const float*)d_in[13];
  float* out = (float*)d_out;

  char* ws = (char*)d_ws;
  size_t off = 0;
  auto alloc = [&](size_t bytes) -> void* {
    void* q = ws + off; off += (bytes + 255) & ~(size_t)255; return q;
  };
  bf16* Wc0 = (bf16*)alloc((size_t)FH * K0 * 2);
  bf16* Wc1 = (bf16*)alloc((size_t)FH * K1 * 2);
  bf16* Wo  = (bf16*)alloc((size_t)112 * H_ * 2);
  float* bs0 = (float*)alloc((size_t)FH * 4);
  float* bs1 = (float*)alloc((size_t)FH * 4);
  bf16* P0[2] = {(bf16*)alloc((size_t)B_ * LDP * 2), (bf16*)alloc((size_t)B_ * LDP * 2)};
  bf16* X1[2] = {(bf16*)alloc((size_t)B_ * LDX1 * 2), (bf16*)alloc((size_t)B_ * LDX1 * 2)};
  float* c0  = (float*)alloc((size_t)B_ * H_ * 4);
  float* c1  = (float*)alloc((size_t)B_ * H_ * 4);
  float* prev = (float*)alloc((size_t)B_ * 112 * 4);

  pack_w0<<<FH, 256, 0, stream>>>(Wih0, Whh0, Wc0);
  pack_w1<<<FH, 256, 0, stream>>>(Wih1, Whh1, Wc1);
  pack_wo<<<112, 256, 0, stream>>>(Wout, Wo);
  pack_bias<<<(FH + 255) / 256, 256, 0, stream>>>(bih0, bhh0, bih1, bhh1, bs0, bs1);
  init_prev<<<(B_ * 128) / 256, 256, 0, stream>>>(p, prev, P0[0], P0[1]);
  init_state<<<dim3(3, B_), 256, 0, stream>>>(hs, cs, gts, X1[1], X1[0], c0, c1);

  for (int t = 0; t < SEQ; ++t) {
    const int cur = t & 1, nxt = cur ^ 1;
    // layer 0: A = [P0[cur] | X1[nxt] cols 0..2112 (h0n(t-1))];
    //          writes c0, h0n(t) -> X1[cur] cols 0..
    lstm_gemm_cell<<<528, 256, 0, stream>>>(
        P0[cur], X1[nxt], 4, K0, Wc0, bs0, c0, X1[cur]);
    // layer 1: A = X1[cur] = [h0n(t) | h1(t-1)]; writes c1, h1n(t) -> X1[nxt]+2112
    lstm_gemm_cell<<<528, 256, 0, stream>>>(
        (const bf16*)nullptr, X1[cur], 0, K1, Wc1, bs1, c1, X1[nxt] + 2112);
    // out: pre = h1n @ W_out + b_out + prev; writes out[:,t,:], prev, P0[nxt] cols 0..99
    out_gemm<<<256, 256, 0, stream>>>(X1[nxt] + 2112, Wo, bout, prev, P0[nxt], out, t);
  }
}